// Round 2
// baseline (255.543 us; speedup 1.0000x reference)
//
#include <hip/hip_runtime.h>
#include <hip/hip_bf16.h>

typedef __bf16 bf16;
typedef bf16 bf16x8 __attribute__((ext_vector_type(8)));
typedef float f32x4 __attribute__((ext_vector_type(4)));

#define DHEAD 128
#define SCALE 0.08838834764831843f   // 1/sqrt(128)
#define LOG2E 1.4426950408889634f

// Flash-attention forward, causal, fp32 in/out, bf16 MFMA compute.
// Block: 256 threads = 4 waves; each block = one (batch, 64-row Q tile);
// each wave owns 16 Q rows. KV tiles of 32 staged in LDS.
__global__ __launch_bounds__(256) void fa_fwd(
    const float* __restrict__ Q, const float* __restrict__ K,
    const float* __restrict__ V, float* __restrict__ O, int S)
{
  const int b    = blockIdx.y;
  const int qt   = blockIdx.x;
  const int tid  = threadIdx.x;
  const int wave = tid >> 6;
  const int lane = tid & 63;
  const int lr   = lane & 15;   // col index within 16-wide fragment
  const int lg   = lane >> 4;   // 4-lane-group id (0..3)

  // +8 bf16 pad keeps rows 16B-aligned and breaks the stride-256B bank conflict
  __shared__ bf16 Ks[32][136];
  __shared__ bf16 Vs[32][136];
  __shared__ bf16 Ps[4][16][40];  // per-wave P transpose buffer (C-layout -> A-layout)

  const size_t bo = (size_t)b * S * DHEAD;
  const float* Qb = Q + bo + (size_t)qt * 64 * DHEAD;
  const float* Kb = K + bo;
  const float* Vb = V + bo;

  const int wrow0 = qt * 64 + wave * 16;  // first global q-row of this wave

  // ---- Q fragments (A operand): lane holds Q[row=lr][d = c*32 + lg*8 + j]
  bf16x8 qf[4];
  {
    const float* qr = Qb + (size_t)(wave * 16 + lr) * DHEAD;
    #pragma unroll
    for (int c = 0; c < 4; ++c) {
      const float4 u0 = *reinterpret_cast<const float4*>(qr + c * 32 + lg * 8);
      const float4 u1 = *reinterpret_cast<const float4*>(qr + c * 32 + lg * 8 + 4);
      bf16x8 f;
      f[0] = (bf16)u0.x; f[1] = (bf16)u0.y; f[2] = (bf16)u0.z; f[3] = (bf16)u0.w;
      f[4] = (bf16)u1.x; f[5] = (bf16)u1.y; f[6] = (bf16)u1.z; f[7] = (bf16)u1.w;
      qf[c] = f;
    }
  }

  f32x4 oacc[8];
  #pragma unroll
  for (int i = 0; i < 8; ++i) oacc[i] = (f32x4){0.f, 0.f, 0.f, 0.f};
  float m[4], l[4];
  #pragma unroll
  for (int r = 0; r < 4; ++r) { m[r] = -__builtin_inff(); l[r] = 0.f; }

  const int kv_end = qt * 64 + 64;
  for (int kc = 0; kc < kv_end; kc += 32) {
    // ---- stage K,V tile (fp32 -> bf16), coalesced float4 loads
    #pragma unroll
    for (int i = 0; i < 4; ++i) {
      const int flat = i * 256 + tid;       // 0..1023
      const int row  = flat >> 5;           // 0..31
      const int d4   = (flat & 31) << 2;    // 0..124
      const float4 k4 = *reinterpret_cast<const float4*>(Kb + (size_t)(kc + row) * DHEAD + d4);
      Ks[row][d4 + 0] = (bf16)k4.x; Ks[row][d4 + 1] = (bf16)k4.y;
      Ks[row][d4 + 2] = (bf16)k4.z; Ks[row][d4 + 3] = (bf16)k4.w;
      const float4 v4 = *reinterpret_cast<const float4*>(Vb + (size_t)(kc + row) * DHEAD + d4);
      Vs[row][d4 + 0] = (bf16)v4.x; Vs[row][d4 + 1] = (bf16)v4.y;
      Vs[row][d4 + 2] = (bf16)v4.z; Vs[row][d4 + 3] = (bf16)v4.w;
    }
    __syncthreads();

    if (kc <= wrow0 + 15) {   // tile not fully masked for this wave
      // ---- scores: S = Q · K^T  (two 16-col subtiles)
      f32x4 s0 = {0.f, 0.f, 0.f, 0.f}, s1 = {0.f, 0.f, 0.f, 0.f};
      #pragma unroll
      for (int c = 0; c < 4; ++c) {
        const bf16x8 kf0 = *reinterpret_cast<const bf16x8*>(&Ks[lr][c * 32 + lg * 8]);
        const bf16x8 kf1 = *reinterpret_cast<const bf16x8*>(&Ks[16 + lr][c * 32 + lg * 8]);
        s0 = __builtin_amdgcn_mfma_f32_16x16x32_bf16(qf[c], kf0, s0, 0, 0, 0);
        s1 = __builtin_amdgcn_mfma_f32_16x16x32_bf16(qf[c], kf1, s1, 0, 0, 0);
      }

      // ---- scale + causal mask + tile row-max
      const bool need_mask = (kc + 31 > wrow0);
      float mt[4];
      #pragma unroll
      for (int r = 0; r < 4; ++r) {
        float x0 = s0[r] * SCALE;
        float x1 = s1[r] * SCALE;
        if (need_mask) {
          const int qrow = wrow0 + lg * 4 + r;
          if (kc + lr > qrow)      x0 = -__builtin_inff();
          if (kc + 16 + lr > qrow) x1 = -__builtin_inff();
        }
        s0[r] = x0; s1[r] = x1;
        float v = fmaxf(x0, x1);
        v = fmaxf(v, __shfl_xor(v, 1));
        v = fmaxf(v, __shfl_xor(v, 2));
        v = fmaxf(v, __shfl_xor(v, 4));
        v = fmaxf(v, __shfl_xor(v, 8));
        mt[r] = v;
      }

      // ---- online softmax update
      float alpha[4];
      #pragma unroll
      for (int r = 0; r < 4; ++r) {
        const float mn = fmaxf(m[r], mt[r]);
        alpha[r] = __builtin_exp2f((m[r] - mn) * LOG2E);
        m[r] = mn;
      }
      #pragma unroll
      for (int r = 0; r < 4; ++r) {
        const float p0 = __builtin_exp2f((s0[r] - m[r]) * LOG2E);
        const float p1 = __builtin_exp2f((s1[r] - m[r]) * LOG2E);
        float ls = p0 + p1;
        ls += __shfl_xor(ls, 1);
        ls += __shfl_xor(ls, 2);
        ls += __shfl_xor(ls, 4);
        ls += __shfl_xor(ls, 8);
        l[r] = l[r] * alpha[r] + ls;
        // write P (C-layout) to LDS for A-layout re-read
        Ps[wave][lg * 4 + r][lr]      = (bf16)p0;
        Ps[wave][lg * 4 + r][16 + lr] = (bf16)p1;
      }
      #pragma unroll
      for (int ds = 0; ds < 8; ++ds) {
        #pragma unroll
        for (int r = 0; r < 4; ++r) oacc[ds][r] *= alpha[r];
      }

      // ---- PV: O += P · V   (A = P from LDS, B = V scalar-gathered from LDS)
      const bf16x8 pf = *reinterpret_cast<const bf16x8*>(&Ps[wave][lr][lg * 8]);
      #pragma unroll
      for (int ds = 0; ds < 8; ++ds) {
        bf16x8 vf;
        #pragma unroll
        for (int j = 0; j < 8; ++j) vf[j] = Vs[lg * 8 + j][ds * 16 + lr];
        oacc[ds] = __builtin_amdgcn_mfma_f32_16x16x32_bf16(pf, vf, oacc[ds], 0, 0, 0);
      }
    }
    __syncthreads();
  }

  // ---- epilogue: O = acc / l
  float* Ob = O + bo + (size_t)(qt * 64 + wave * 16) * DHEAD;
  float inv[4];
  #pragma unroll
  for (int r = 0; r < 4; ++r) inv[r] = 1.0f / l[r];
  #pragma unroll
  for (int ds = 0; ds < 8; ++ds) {
    #pragma unroll
    for (int r = 0; r < 4; ++r) {
      Ob[(size_t)(lg * 4 + r) * DHEAD + ds * 16 + lr] = oacc[ds][r] * inv[r];
    }
  }
}

extern "C" void kernel_launch(void* const* d_in, const int* in_sizes, int n_in,
                              void* d_out, int out_size, void* d_ws, size_t ws_size,
                              hipStream_t stream) {
  const float* q = (const float*)d_in[0];
  const float* k = (const float*)d_in[1];
  const float* v = (const float*)d_in[2];
  float* o = (float*)d_out;

  const int B = 16;
  const int S = in_sizes[0] / (B * DHEAD);   // 2048

  dim3 grid(S / 64, B);
  dim3 block(256);
  fa_fwd<<<grid, block, 0, stream>>>(q, k, v, o, S);
}

// Round 5
// 191.608 us; speedup vs baseline: 1.3337x; 1.3337x over previous
//
#include <hip/hip_runtime.h>
#include <hip/hip_bf16.h>

typedef __bf16 bf16;
typedef bf16 bf16x8 __attribute__((ext_vector_type(8)));
typedef bf16 bf16x4 __attribute__((ext_vector_type(4)));
typedef float f32x4 __attribute__((ext_vector_type(4)));

#define DHEAD 128
#define SCALE 0.08838834764831843f   // 1/sqrt(128)
#define LOG2E 1.4426950408889634f

// Flash-attention fwd, causal, fp32 I/O, bf16 MFMA.
// 256 thr = 4 waves; block = (batch, 64-row Q tile); KV tiles of 32,
// double-buffered LDS, ONE barrier per tile, loads issued one tile early.
// V stored transposed (Vt[d][kv]) with 56-elem rows (28-dword stride spreads
// read banks) + 2-bit XOR group swizzle on kv (spreads write banks).
__global__ __launch_bounds__(256) void fa_fwd(
    const float* __restrict__ Q, const float* __restrict__ K,
    const float* __restrict__ V, float* __restrict__ O, int S)
{
  // Balanced dispatch: round-robin puts block bid and bid+256 on the same CU;
  // give them complementary causal depth (sum = 32 tiles-units per CU).
  const int bid = blockIdx.x;
  const int pr  = bid & 255;
  const int hb  = bid >> 8;
  const int b   = pr & 15;
  const int jj  = pr >> 4;               // 0..15
  const int qt  = hb ? jj : (31 - jj);   // long blocks in first wave of dispatch

  const int tid  = threadIdx.x;
  const int wave = tid >> 6;
  const int lane = tid & 63;
  const int lr   = lane & 15;   // fragment col
  const int lg   = lane >> 4;   // fragment k-group

  __shared__ bf16 Ks[2][32][136];      // row-major K, +8 pad
  __shared__ bf16 Vt[2][DHEAD][56];    // transposed V, bank-spread stride
  __shared__ bf16 Ps[4][16][40];       // per-wave P C->A relayout buffer

  const size_t bo = (size_t)b * S * DHEAD;
  const float* Qb = Q + bo + (size_t)qt * 64 * DHEAD;
  const float* Kb = K + bo;
  const float* Vb = V + bo;
  const int wrow0 = qt * 64 + wave * 16;

  // staging coords: thread covers rows {8i + srow}, fixed 16B col d4
  const int srow = tid >> 5;            // 0..7
  const int d4   = (tid & 31) << 2;     // 0..124
  const int vsw  = (d4 >> 4) & 3;       // V write-swizzle group (const per thread)

  // ---- Q fragments: A[row=lr][k=lg*8+j], k-block c
  bf16x8 qf[4];
  {
    const float* qr = Qb + (size_t)(wave * 16 + lr) * DHEAD;
    #pragma unroll
    for (int c = 0; c < 4; ++c) {
      const float4 u0 = *reinterpret_cast<const float4*>(qr + c * 32 + lg * 8);
      const float4 u1 = *reinterpret_cast<const float4*>(qr + c * 32 + lg * 8 + 4);
      bf16x8 f;
      f[0] = (bf16)u0.x; f[1] = (bf16)u0.y; f[2] = (bf16)u0.z; f[3] = (bf16)u0.w;
      f[4] = (bf16)u1.x; f[5] = (bf16)u1.y; f[6] = (bf16)u1.z; f[7] = (bf16)u1.w;
      qf[c] = f;
    }
  }

  f32x4 oacc[8];
  #pragma unroll
  for (int i = 0; i < 8; ++i) oacc[i] = (f32x4){0.f, 0.f, 0.f, 0.f};
  float m[4], l[4];
  #pragma unroll
  for (int r = 0; r < 4; ++r) { m[r] = -__builtin_inff(); l[r] = 0.f; }

  const int nt = 2 * (qt + 1);          // KV tiles of 32
  float4 kreg[4], vreg[4];

  auto load_tile = [&](int kc) {
    #pragma unroll
    for (int i = 0; i < 4; ++i) {
      kreg[i] = *reinterpret_cast<const float4*>(Kb + (size_t)(kc + 8 * i + srow) * DHEAD + d4);
      vreg[i] = *reinterpret_cast<const float4*>(Vb + (size_t)(kc + 8 * i + srow) * DHEAD + d4);
    }
  };
  auto write_tile = [&](int buf) {
    #pragma unroll
    for (int i = 0; i < 4; ++i) {
      const int kv = 8 * i + srow;
      // K row-major: one 8B write
      bf16x4 kp;
      kp[0] = (bf16)kreg[i].x; kp[1] = (bf16)kreg[i].y;
      kp[2] = (bf16)kreg[i].z; kp[3] = (bf16)kreg[i].w;
      *reinterpret_cast<bf16x4*>(&Ks[buf][kv][d4]) = kp;
      // V transposed: 4 scalar writes down column kv (swizzled group)
      const int col = (kv & 7) | (((kv >> 3) ^ vsw) << 3);
      Vt[buf][d4 + 0][col] = (bf16)vreg[i].x;
      Vt[buf][d4 + 1][col] = (bf16)vreg[i].y;
      Vt[buf][d4 + 2][col] = (bf16)vreg[i].z;
      Vt[buf][d4 + 3][col] = (bf16)vreg[i].w;
    }
  };

  load_tile(0);
  write_tile(0);

  int cur = 0;
  for (int t = 0; t < nt; ++t) {
    if (t + 1 < nt) load_tile((t + 1) * 32);   // issue early: latency under compute
    __syncthreads();                            // buf[cur] ready for all waves

    const int kc = t * 32;
    if (kc <= wrow0 + 15) {
      // ---- QK^T
      f32x4 s0 = {0.f, 0.f, 0.f, 0.f}, s1 = {0.f, 0.f, 0.f, 0.f};
      __builtin_amdgcn_s_setprio(1);
      #pragma unroll
      for (int c = 0; c < 4; ++c) {
        const bf16x8 kf0 = *reinterpret_cast<const bf16x8*>(&Ks[cur][lr][c * 32 + lg * 8]);
        const bf16x8 kf1 = *reinterpret_cast<const bf16x8*>(&Ks[cur][16 + lr][c * 32 + lg * 8]);
        s0 = __builtin_amdgcn_mfma_f32_16x16x32_bf16(qf[c], kf0, s0, 0, 0, 0);
        s1 = __builtin_amdgcn_mfma_f32_16x16x32_bf16(qf[c], kf1, s1, 0, 0, 0);
      }
      __builtin_amdgcn_s_setprio(0);

      // ---- scale + causal mask + tile row-max
      const bool need_mask = (kc + 31 > wrow0);
      float mt[4];
      #pragma unroll
      for (int r = 0; r < 4; ++r) {
        float x0 = s0[r] * SCALE;
        float x1 = s1[r] * SCALE;
        if (need_mask) {
          const int qrow = wrow0 + lg * 4 + r;
          if (kc + lr > qrow)      x0 = -__builtin_inff();
          if (kc + 16 + lr > qrow) x1 = -__builtin_inff();
        }
        s0[r] = x0; s1[r] = x1;
        float v = fmaxf(x0, x1);
        v = fmaxf(v, __shfl_xor(v, 1));
        v = fmaxf(v, __shfl_xor(v, 2));
        v = fmaxf(v, __shfl_xor(v, 4));
        v = fmaxf(v, __shfl_xor(v, 8));
        mt[r] = v;
      }

      // ---- online softmax update
      float alpha[4];
      #pragma unroll
      for (int r = 0; r < 4; ++r) {
        const float mn = fmaxf(m[r], mt[r]);
        alpha[r] = __builtin_exp2f((m[r] - mn) * LOG2E);
        m[r] = mn;
      }
      #pragma unroll
      for (int r = 0; r < 4; ++r) {
        const float p0 = __builtin_exp2f((s0[r] - m[r]) * LOG2E);
        const float p1 = __builtin_exp2f((s1[r] - m[r]) * LOG2E);
        float ls = p0 + p1;
        ls += __shfl_xor(ls, 1);
        ls += __shfl_xor(ls, 2);
        ls += __shfl_xor(ls, 4);
        ls += __shfl_xor(ls, 8);
        l[r] = l[r] * alpha[r] + ls;
        Ps[wave][lg * 4 + r][lr]      = (bf16)p0;
        Ps[wave][lg * 4 + r][16 + lr] = (bf16)p1;
      }
      #pragma unroll
      for (int ds = 0; ds < 8; ++ds) {
        #pragma unroll
        for (int r = 0; r < 4; ++r) oacc[ds][r] *= alpha[r];
      }

      // ---- PV: A = P (LDS), B = V via contiguous 16B reads from Vt
      const bf16x8 pf = *reinterpret_cast<const bf16x8*>(&Ps[wave][lr][lg * 8]);
      __builtin_amdgcn_s_setprio(1);
      #pragma unroll
      for (int ds = 0; ds < 8; ++ds) {
        const int d  = ds * 16 + lr;
        const int sg = (lg ^ (ds & 3)) << 3;   // inverse of write swizzle
        const bf16x8 vf = *reinterpret_cast<const bf16x8*>(&Vt[cur][d][sg]);
        oacc[ds] = __builtin_amdgcn_mfma_f32_16x16x32_bf16(pf, vf, oacc[ds], 0, 0, 0);
      }
      __builtin_amdgcn_s_setprio(0);
    }

    if (t + 1 < nt) write_tile(cur ^ 1);        // safe: barrier gated reuse
    cur ^= 1;
  }

  // ---- epilogue
  float* Ob = O + bo + (size_t)(qt * 64 + wave * 16) * DHEAD;
  float inv[4];
  #pragma unroll
  for (int r = 0; r < 4; ++r) inv[r] = 1.0f / l[r];
  #pragma unroll
  for (int ds = 0; ds < 8; ++ds) {
    #pragma unroll
    for (int r = 0; r < 4; ++r) {
      Ob[(size_t)(lg * 4 + r) * DHEAD + ds * 16 + lr] = oacc[ds][r] * inv[r];
    }
  }
}

extern "C" void kernel_launch(void* const* d_in, const int* in_sizes, int n_in,
                              void* d_out, int out_size, void* d_ws, size_t ws_size,
                              hipStream_t stream) {
  const float* q = (const float*)d_in[0];
  const float* k = (const float*)d_in[1];
  const float* v = (const float*)d_in[2];
  float* o = (float*)d_out;

  const int B = 16;
  const int S = in_sizes[0] / (B * DHEAD);   // 2048

  dim3 grid(512);
  dim3 block(256);
  fa_fwd<<<grid, block, 0, stream>>>(q, k, v, o, S);
}

// Round 9
// 162.695 us; speedup vs baseline: 1.5707x; 1.1777x over previous
//
#include <hip/hip_runtime.h>
#include <hip/hip_bf16.h>

typedef __bf16 bf16;
typedef bf16 bf16x8 __attribute__((ext_vector_type(8)));
typedef bf16 bf16x4 __attribute__((ext_vector_type(4)));
typedef float f32x4 __attribute__((ext_vector_type(4)));

#define DHEAD 128
#define SCL2 0.1275500811965365f   // (1/sqrt(128)) * log2(e)
#define NINF (-__builtin_inff())

__device__ __forceinline__ unsigned pk2(float a, float b) {
  bf16 x = (bf16)a, y = (bf16)b;
  unsigned short ux = __builtin_bit_cast(unsigned short, x);
  unsigned short uy = __builtin_bit_cast(unsigned short, y);
  return ((unsigned)uy << 16) | (unsigned)ux;
}

// Flash-attention fwd, causal, fp32 I/O, bf16 MFMA.
// Swapped QK^T (S^T = mfma(K,Q)): score col = q = lane&15 -> in-lane softmax,
// only 2 shfls per reduce. Defer-max (THR=8) skips most rescales.
// V staged as pairs (b32 writes, 4-way max) into Vt[128][40] with 2-bit XOR
// swizzle on pair bits 2-3 (read-compatible with aligned b128 reads).
// Pipeline: barrier -> write prev-loaded tile -> issue loads 2-ahead -> compute.
__global__ __launch_bounds__(256) void fa_fwd(
    const float* __restrict__ Q, const float* __restrict__ K,
    const float* __restrict__ V, float* __restrict__ O, int S)
{
  // balanced dispatch: block c and c+256 share a CU, complementary causal depth
  const int bid = blockIdx.x;
  const int prb = bid & 255;
  const int hb  = bid >> 8;
  const int b   = prb & 15;
  const int jj  = prb >> 4;
  const int qt  = hb ? jj : (31 - jj);

  const int tid  = threadIdx.x;
  const int wave = tid >> 6;
  const int lane = tid & 63;
  const int lr   = lane & 15;   // q-column (swapped QK) / d-column (PV out)
  const int lg   = lane >> 4;   // k-group

  __shared__ bf16 Ks[2][32][136];     // row-major K, +8 pad
  __shared__ bf16 Vt[2][DHEAD][40];   // V-transposed pairs, swizzled
  __shared__ bf16 Ps[4][16][40];      // per-wave P[q][k] relayout buffer

  const size_t bo = (size_t)b * S * DHEAD;
  const float* Qb = Q + bo + (size_t)qt * 64 * DHEAD;
  const float* Kb = K + bo;
  const float* Vb = V + bo;
  const int wrow0 = qt * 64 + wave * 16;

  // staging coords: thread owns d-quad d4 and kv-pairs {prw, prw+8}
  const int j   = tid & 31;
  const int prw = tid >> 5;
  const int d4  = j << 2;
  const int Gw  = (j >> 1) & 3;      // = (d>>3)&3 for d in d4..d4+3

  // ---- Q fragments (B operand): col=lane&15=q-row, k=lg*8+j
  bf16x8 qf[4];
  {
    const float* qr = Qb + (size_t)(wave * 16 + lr) * DHEAD;
    #pragma unroll
    for (int c = 0; c < 4; ++c) {
      const float4 u0 = *reinterpret_cast<const float4*>(qr + c * 32 + lg * 8);
      const float4 u1 = *reinterpret_cast<const float4*>(qr + c * 32 + lg * 8 + 4);
      bf16x8 f;
      f[0] = (bf16)u0.x; f[1] = (bf16)u0.y; f[2] = (bf16)u0.z; f[3] = (bf16)u0.w;
      f[4] = (bf16)u1.x; f[5] = (bf16)u1.y; f[6] = (bf16)u1.z; f[7] = (bf16)u1.w;
      qf[c] = f;
    }
  }

  f32x4 oacc[8];
  #pragma unroll
  for (int i = 0; i < 8; ++i) oacc[i] = (f32x4){0.f, 0.f, 0.f, 0.f};
  float m = NINF, l = 0.f;

  const int nt = 2 * (qt + 1);
  float4 kA[2], kB[2], vA[2], vB[2];

  auto load_tile = [&](int kc) {
    #pragma unroll
    for (int ps = 0; ps < 2; ++ps) {
      const int kv = kc + 2 * (prw + 8 * ps);
      const float* kp = Kb + (size_t)kv * DHEAD + d4;
      const float* vp = Vb + (size_t)kv * DHEAD + d4;
      kA[ps] = *reinterpret_cast<const float4*>(kp);
      kB[ps] = *reinterpret_cast<const float4*>(kp + DHEAD);
      vA[ps] = *reinterpret_cast<const float4*>(vp);
      vB[ps] = *reinterpret_cast<const float4*>(vp + DHEAD);
    }
  };
  auto write_tile = [&](int buf) {
    #pragma unroll
    for (int ps = 0; ps < 2; ++ps) {
      const int kvp = prw + 8 * ps;
      bf16x4 ka, kb;
      ka[0] = (bf16)kA[ps].x; ka[1] = (bf16)kA[ps].y;
      ka[2] = (bf16)kA[ps].z; ka[3] = (bf16)kA[ps].w;
      kb[0] = (bf16)kB[ps].x; kb[1] = (bf16)kB[ps].y;
      kb[2] = (bf16)kB[ps].z; kb[3] = (bf16)kB[ps].w;
      *reinterpret_cast<bf16x4*>(&Ks[buf][2 * kvp][d4])     = ka;
      *reinterpret_cast<bf16x4*>(&Ks[buf][2 * kvp + 1][d4]) = kb;
      const int pS = kvp ^ (Gw << 2);   // swizzle pair bits 2-3 by d-hash
      const float* fa = &vA[ps].x;
      const float* fb = &vB[ps].x;
      #pragma unroll
      for (int c = 0; c < 4; ++c) {
        *reinterpret_cast<unsigned*>(&Vt[buf][d4 + c][2 * pS]) = pk2(fa[c], fb[c]);
      }
    }
  };

  load_tile(0);
  write_tile(0);
  if (nt > 1) load_tile(32);

  int cur = 0;
  for (int t = 0; t < nt; ++t) {
    __syncthreads();                       // buf[cur] ready; prev reads of cur^1 done
    if (t + 1 < nt) write_tile(cur ^ 1);   // regs hold tile t+1 (loaded last iter)
    if (t + 2 < nt) load_tile((t + 2) * 32);

    const int kc = t * 32;
    if (kc <= wrow0 + 15) {
      // ---- S^T = K·Q^T : lane holds S[kv=4lg+r][q=lr] (s0), +16 (s1)
      f32x4 s0 = {0.f, 0.f, 0.f, 0.f}, s1 = {0.f, 0.f, 0.f, 0.f};
      __builtin_amdgcn_s_setprio(1);
      #pragma unroll
      for (int c = 0; c < 4; ++c) {
        const bf16x8 kf0 = *reinterpret_cast<const bf16x8*>(&Ks[cur][lr][c * 32 + lg * 8]);
        const bf16x8 kf1 = *reinterpret_cast<const bf16x8*>(&Ks[cur][16 + lr][c * 32 + lg * 8]);
        s0 = __builtin_amdgcn_mfma_f32_16x16x32_bf16(kf0, qf[c], s0, 0, 0, 0);
        s1 = __builtin_amdgcn_mfma_f32_16x16x32_bf16(kf1, qf[c], s1, 0, 0, 0);
      }
      __builtin_amdgcn_s_setprio(0);

      // ---- scale(+mask) in log2 domain; in-lane + 2-shfl row-max
      const int qg = wrow0 + lr;
      float x0[4], x1[4];
      if (kc + 31 > wrow0) {
        #pragma unroll
        for (int r = 0; r < 4; ++r) {
          x0[r] = (kc + 4 * lg + r      > qg) ? NINF : s0[r] * SCL2;
          x1[r] = (kc + 16 + 4 * lg + r > qg) ? NINF : s1[r] * SCL2;
        }
      } else {
        #pragma unroll
        for (int r = 0; r < 4; ++r) { x0[r] = s0[r] * SCL2; x1[r] = s1[r] * SCL2; }
      }
      float tm = NINF;
      #pragma unroll
      for (int r = 0; r < 4; ++r) tm = fmaxf(tm, fmaxf(x0[r], x1[r]));
      tm = fmaxf(tm, __shfl_xor(tm, 16));
      tm = fmaxf(tm, __shfl_xor(tm, 32));

      // ---- defer-max: rescale only when max grew past THR=8
      if (!__all(tm <= m + 8.0f)) {
        const float mn = fmaxf(m, tm);
        const float al = __builtin_exp2f(m - mn);
        m = mn; l *= al;
        #pragma unroll
        for (int r = 0; r < 4; ++r) {
          const float ar = __shfl(al, 4 * lg + r);
          #pragma unroll
          for (int ds = 0; ds < 8; ++ds) oacc[ds][r] *= ar;
        }
      }

      // ---- P = exp2(x - m); in-lane + 2-shfl row-sum
      float p0[4], p1[4];
      float ts = 0.f;
      #pragma unroll
      for (int r = 0; r < 4; ++r) {
        p0[r] = __builtin_exp2f(x0[r] - m);
        p1[r] = __builtin_exp2f(x1[r] - m);
        ts += p0[r] + p1[r];
      }
      ts += __shfl_xor(ts, 16);
      ts += __shfl_xor(ts, 32);
      l += ts;

      // ---- P -> Ps[q][k] (paired b32 writes), then A-frag read
      *reinterpret_cast<unsigned*>(&Ps[wave][lr][4 * lg])          = pk2(p0[0], p0[1]);
      *reinterpret_cast<unsigned*>(&Ps[wave][lr][4 * lg + 2])      = pk2(p0[2], p0[3]);
      *reinterpret_cast<unsigned*>(&Ps[wave][lr][16 + 4 * lg])     = pk2(p1[0], p1[1]);
      *reinterpret_cast<unsigned*>(&Ps[wave][lr][16 + 4 * lg + 2]) = pk2(p1[2], p1[3]);

      const bf16x8 pf = *reinterpret_cast<const bf16x8*>(&Ps[wave][lr][lg * 8]);
      __builtin_amdgcn_s_setprio(1);
      #pragma unroll
      for (int ds = 0; ds < 8; ++ds) {
        const int G = (2 * ds + (lr >> 3)) & 3;   // read-side of write swizzle
        const bf16x8 vf = *reinterpret_cast<const bf16x8*>(&Vt[cur][ds * 16 + lr][8 * (lg ^ G)]);
        oacc[ds] = __builtin_amdgcn_mfma_f32_16x16x32_bf16(pf, vf, oacc[ds], 0, 0, 0);
      }
      __builtin_amdgcn_s_setprio(0);
    }
    cur ^= 1;
  }

  // ---- epilogue: O = acc / l  (l lives at q=lane&15; gather per oacc row)
  const float linv = 1.0f / l;
  float* Ob = O + bo + (size_t)(qt * 64 + wave * 16) * DHEAD;
  #pragma unroll
  for (int r = 0; r < 4; ++r) {
    const float ir = __shfl(linv, 4 * lg + r);
    #pragma unroll
    for (int ds = 0; ds < 8; ++ds) {
      Ob[(size_t)(4 * lg + r) * DHEAD + ds * 16 + lr] = oacc[ds][r] * ir;
    }
  }
}

extern "C" void kernel_launch(void* const* d_in, const int* in_sizes, int n_in,
                              void* d_out, int out_size, void* d_ws, size_t ws_size,
                              hipStream_t stream) {
  const float* q = (const float*)d_in[0];
  const float* k = (const float*)d_in[1];
  const float* v = (const float*)d_in[2];
  float* o = (float*)d_out;

  const int B = 16;
  const int S = in_sizes[0] / (B * DHEAD);   // 2048

  dim3 grid(512);
  dim3 block(256);
  fa_fwd<<<grid, block, 0, stream>>>(q, k, v, o, S);
}

// Round 11
// 161.058 us; speedup vs baseline: 1.5867x; 1.0102x over previous
//
#include <hip/hip_runtime.h>
#include <hip/hip_bf16.h>

typedef __bf16 bf16;
typedef bf16 bf16x8 __attribute__((ext_vector_type(8)));
typedef bf16 bf16x4 __attribute__((ext_vector_type(4)));
typedef float f32x4 __attribute__((ext_vector_type(4)));

#define DHEAD 128
#define SCL2 0.1275500811965365f   // (1/sqrt(128)) * log2(e)
#define NINF (-__builtin_inff())

__device__ __forceinline__ unsigned pk2(float a, float b) {
  bf16 x = (bf16)a, y = (bf16)b;
  unsigned short ux = __builtin_bit_cast(unsigned short, x);
  unsigned short uy = __builtin_bit_cast(unsigned short, y);
  return ((unsigned)uy << 16) | (unsigned)ux;
}

// ===================== split-KV kernel (primary path) =====================
// Each (b, qt) is split into 2 half-KV blocks of (qt+1) tiles each.
// Inner tile loop identical to the verified R5 kernel; epilogue writes
// unnormalized acc + (m,l) to workspace. fa_merge combines the halves.
// ws layout: acc fp32 [1024][64][128] then ml fp32 [1024][64][2].
#define ACC_FLOATS (1024 * 64 * 128)
#define ML_OFF ACC_FLOATS
#define WS_NEED ((size_t)(ACC_FLOATS + 1024 * 64 * 2) * 4)

__global__ __launch_bounds__(256) void fa_split(
    const float* __restrict__ Q, const float* __restrict__ K,
    const float* __restrict__ V, float* __restrict__ ws, int S)
{
  // dispatch rounds of 256: r0=(hi qt, h0), r1=(hi qt, h1), r2=(lo,h0), r3=(lo,h1)
  // -> CU i hosts chains {32-idx, 32-idx, idx+1, idx+1}: 66 tile-units each.
  const int bid  = blockIdx.x;
  const int r    = bid >> 8;
  const int i    = bid & 255;
  const int b    = i & 15;
  const int idx  = i >> 4;                  // 0..15
  const int qt   = (r < 2) ? (31 - idx) : idx;
  const int half = r & 1;
  const int blk  = bid;                     // ws slot

  const int t0 = half * (qt + 1);
  const int t1 = t0 + (qt + 1);

  const int tid  = threadIdx.x;
  const int wave = tid >> 6;
  const int lane = tid & 63;
  const int lr   = lane & 15;
  const int lg   = lane >> 4;

  __shared__ bf16 Ks[2][32][136];
  __shared__ bf16 Vt[2][DHEAD][40];
  __shared__ bf16 Ps[4][16][40];

  const size_t bo = (size_t)b * S * DHEAD;
  const float* Qb = Q + bo + (size_t)qt * 64 * DHEAD;
  const float* Kb = K + bo;
  const float* Vb = V + bo;
  const int wrow0 = qt * 64 + wave * 16;

  const int j   = tid & 31;
  const int prw = tid >> 5;
  const int d4  = j << 2;
  const int Gw  = (j >> 1) & 3;

  bf16x8 qf[4];
  {
    const float* qr = Qb + (size_t)(wave * 16 + lr) * DHEAD;
    #pragma unroll
    for (int c = 0; c < 4; ++c) {
      const float4 u0 = *reinterpret_cast<const float4*>(qr + c * 32 + lg * 8);
      const float4 u1 = *reinterpret_cast<const float4*>(qr + c * 32 + lg * 8 + 4);
      bf16x8 f;
      f[0] = (bf16)u0.x; f[1] = (bf16)u0.y; f[2] = (bf16)u0.z; f[3] = (bf16)u0.w;
      f[4] = (bf16)u1.x; f[5] = (bf16)u1.y; f[6] = (bf16)u1.z; f[7] = (bf16)u1.w;
      qf[c] = f;
    }
  }

  f32x4 oacc[8];
  #pragma unroll
  for (int ii = 0; ii < 8; ++ii) oacc[ii] = (f32x4){0.f, 0.f, 0.f, 0.f};
  float m = NINF, l = 0.f;

  float4 kA[2], kB[2], vA[2], vB[2];
  auto load_tile = [&](int kc) {
    #pragma unroll
    for (int ps = 0; ps < 2; ++ps) {
      const int kv = kc + 2 * (prw + 8 * ps);
      const float* kp = Kb + (size_t)kv * DHEAD + d4;
      const float* vp = Vb + (size_t)kv * DHEAD + d4;
      kA[ps] = *reinterpret_cast<const float4*>(kp);
      kB[ps] = *reinterpret_cast<const float4*>(kp + DHEAD);
      vA[ps] = *reinterpret_cast<const float4*>(vp);
      vB[ps] = *reinterpret_cast<const float4*>(vp + DHEAD);
    }
  };
  auto write_tile = [&](int buf) {
    #pragma unroll
    for (int ps = 0; ps < 2; ++ps) {
      const int kvp = prw + 8 * ps;
      bf16x4 ka, kb;
      ka[0] = (bf16)kA[ps].x; ka[1] = (bf16)kA[ps].y;
      ka[2] = (bf16)kA[ps].z; ka[3] = (bf16)kA[ps].w;
      kb[0] = (bf16)kB[ps].x; kb[1] = (bf16)kB[ps].y;
      kb[2] = (bf16)kB[ps].z; kb[3] = (bf16)kB[ps].w;
      *reinterpret_cast<bf16x4*>(&Ks[buf][2 * kvp][d4])     = ka;
      *reinterpret_cast<bf16x4*>(&Ks[buf][2 * kvp + 1][d4]) = kb;
      const int pS = kvp ^ (Gw << 2);
      const float* fa = &vA[ps].x;
      const float* fb = &vB[ps].x;
      #pragma unroll
      for (int c = 0; c < 4; ++c) {
        *reinterpret_cast<unsigned*>(&Vt[buf][d4 + c][2 * pS]) = pk2(fa[c], fb[c]);
      }
    }
  };

  load_tile(t0 * 32);
  write_tile(0);
  if (t0 + 1 < t1) load_tile((t0 + 1) * 32);

  int cur = 0;
  for (int t = t0; t < t1; ++t) {
    __syncthreads();
    if (t + 1 < t1) write_tile(cur ^ 1);
    if (t + 2 < t1) load_tile((t + 2) * 32);

    const int kc = t * 32;
    if (kc <= wrow0 + 15) {
      f32x4 s0 = {0.f, 0.f, 0.f, 0.f}, s1 = {0.f, 0.f, 0.f, 0.f};
      __builtin_amdgcn_s_setprio(1);
      #pragma unroll
      for (int c = 0; c < 4; ++c) {
        const bf16x8 kf0 = *reinterpret_cast<const bf16x8*>(&Ks[cur][lr][c * 32 + lg * 8]);
        const bf16x8 kf1 = *reinterpret_cast<const bf16x8*>(&Ks[cur][16 + lr][c * 32 + lg * 8]);
        s0 = __builtin_amdgcn_mfma_f32_16x16x32_bf16(kf0, qf[c], s0, 0, 0, 0);
        s1 = __builtin_amdgcn_mfma_f32_16x16x32_bf16(kf1, qf[c], s1, 0, 0, 0);
      }
      __builtin_amdgcn_s_setprio(0);

      const int qg = wrow0 + lr;
      float x0[4], x1[4];
      if (kc + 31 > wrow0) {
        #pragma unroll
        for (int rr = 0; rr < 4; ++rr) {
          x0[rr] = (kc + 4 * lg + rr      > qg) ? NINF : s0[rr] * SCL2;
          x1[rr] = (kc + 16 + 4 * lg + rr > qg) ? NINF : s1[rr] * SCL2;
        }
      } else {
        #pragma unroll
        for (int rr = 0; rr < 4; ++rr) { x0[rr] = s0[rr] * SCL2; x1[rr] = s1[rr] * SCL2; }
      }
      float tm = NINF;
      #pragma unroll
      for (int rr = 0; rr < 4; ++rr) tm = fmaxf(tm, fmaxf(x0[rr], x1[rr]));
      tm = fmaxf(tm, __shfl_xor(tm, 16));
      tm = fmaxf(tm, __shfl_xor(tm, 32));

      if (!__all(tm <= m + 8.0f)) {
        const float mn = fmaxf(m, tm);
        const float al = __builtin_exp2f(m - mn);
        m = mn; l *= al;
        #pragma unroll
        for (int rr = 0; rr < 4; ++rr) {
          const float ar = __shfl(al, 4 * lg + rr);
          #pragma unroll
          for (int ds = 0; ds < 8; ++ds) oacc[ds][rr] *= ar;
        }
      }

      float p0[4], p1[4];
      float ts = 0.f;
      #pragma unroll
      for (int rr = 0; rr < 4; ++rr) {
        p0[rr] = __builtin_exp2f(x0[rr] - m);
        p1[rr] = __builtin_exp2f(x1[rr] - m);
        ts += p0[rr] + p1[rr];
      }
      ts += __shfl_xor(ts, 16);
      ts += __shfl_xor(ts, 32);
      l += ts;

      *reinterpret_cast<unsigned*>(&Ps[wave][lr][4 * lg])          = pk2(p0[0], p0[1]);
      *reinterpret_cast<unsigned*>(&Ps[wave][lr][4 * lg + 2])      = pk2(p0[2], p0[3]);
      *reinterpret_cast<unsigned*>(&Ps[wave][lr][16 + 4 * lg])     = pk2(p1[0], p1[1]);
      *reinterpret_cast<unsigned*>(&Ps[wave][lr][16 + 4 * lg + 2]) = pk2(p1[2], p1[3]);

      const bf16x8 pf = *reinterpret_cast<const bf16x8*>(&Ps[wave][lr][lg * 8]);
      __builtin_amdgcn_s_setprio(1);
      #pragma unroll
      for (int ds = 0; ds < 8; ++ds) {
        const int G = (2 * ds + (lr >> 3)) & 3;
        const bf16x8 vf = *reinterpret_cast<const bf16x8*>(&Vt[cur][ds * 16 + lr][8 * (lg ^ G)]);
        oacc[ds] = __builtin_amdgcn_mfma_f32_16x16x32_bf16(pf, vf, oacc[ds], 0, 0, 0);
      }
      __builtin_amdgcn_s_setprio(0);
    }
    cur ^= 1;
  }

  // epilogue: unnormalized acc + (m,l) to workspace
  float* aw = ws + (size_t)blk * 8192 + (size_t)(wave * 16) * 128;
  #pragma unroll
  for (int rr = 0; rr < 4; ++rr) {
    #pragma unroll
    for (int ds = 0; ds < 8; ++ds) {
      aw[(4 * lg + rr) * 128 + ds * 16 + lr] = oacc[ds][rr];
    }
  }
  if (lg == 0) {
    float* mlp = ws + ML_OFF + (size_t)(blk * 64 + wave * 16 + lr) * 2;
    mlp[0] = m;
    mlp[1] = l;
  }
}

// ===================== merge kernel =====================
__global__ __launch_bounds__(256) void fa_merge(
    const float* __restrict__ ws, float* __restrict__ O, int S)
{
  const int blk2 = blockIdx.x;          // (b*32 + qt), 512 total
  const int b  = blk2 >> 5;
  const int qt = blk2 & 31;
  const int tid = threadIdx.x;
  const int row = tid >> 2;             // 0..63
  const int c0  = (tid & 3) * 32;       // 0..96

  // locate the two half-blocks for this (b, qt) in dispatch-round order:
  // qt>=16: rounds 0/1 at idx=31-qt; qt<16: rounds 2/3 at idx=qt.
  const int idx  = (qt >= 16) ? (31 - qt) : qt;
  const int base = (qt >= 16) ? 0 : 512;
  const int blk0 = base + (idx << 4) + b;          // half 0
  const int blk1 = blk0 + 256;                     // half 1

  const float* ml0 = ws + ML_OFF + (size_t)(blk0 * 64 + row) * 2;
  const float* ml1 = ws + ML_OFF + (size_t)(blk1 * 64 + row) * 2;
  const float m0 = ml0[0], l0 = ml0[1];
  const float m1 = ml1[0], l1 = ml1[1];
  const float mm = fmaxf(m0, m1);
  const float a0 = __builtin_exp2f(m0 - mm);
  const float a1 = __builtin_exp2f(m1 - mm);
  const float inv = 1.0f / (a0 * l0 + a1 * l1);

  const float* w0 = ws + (size_t)blk0 * 8192 + (size_t)row * 128 + c0;
  const float* w1 = ws + (size_t)blk1 * 8192 + (size_t)row * 128 + c0;
  float* out = O + ((size_t)b * S + qt * 64 + row) * DHEAD + c0;

  #pragma unroll
  for (int qd = 0; qd < 8; ++qd) {
    const float4 u0 = *reinterpret_cast<const float4*>(w0 + qd * 4);
    const float4 u1 = *reinterpret_cast<const float4*>(w1 + qd * 4);
    float4 o;
    o.x = (a0 * u0.x + a1 * u1.x) * inv;
    o.y = (a0 * u0.y + a1 * u1.y) * inv;
    o.z = (a0 * u0.z + a1 * u1.z) * inv;
    o.w = (a0 * u0.w + a1 * u1.w) * inv;
    *reinterpret_cast<float4*>(out + qd * 4) = o;
  }
}

// ===================== fallback (verified R5 kernel, unchanged) =====================
__global__ __launch_bounds__(256) void fa_fwd(
    const float* __restrict__ Q, const float* __restrict__ K,
    const float* __restrict__ V, float* __restrict__ O, int S)
{
  const int bid = blockIdx.x;
  const int prb = bid & 255;
  const int hb  = bid >> 8;
  const int b   = prb & 15;
  const int jj  = prb >> 4;
  const int qt  = hb ? jj : (31 - jj);

  const int tid  = threadIdx.x;
  const int wave = tid >> 6;
  const int lane = tid & 63;
  const int lr   = lane & 15;
  const int lg   = lane >> 4;

  __shared__ bf16 Ks[2][32][136];
  __shared__ bf16 Vt[2][DHEAD][40];
  __shared__ bf16 Ps[4][16][40];

  const size_t bo = (size_t)b * S * DHEAD;
  const float* Qb = Q + bo + (size_t)qt * 64 * DHEAD;
  const float* Kb = K + bo;
  const float* Vb = V + bo;
  const int wrow0 = qt * 64 + wave * 16;

  const int j   = tid & 31;
  const int prw = tid >> 5;
  const int d4  = j << 2;
  const int Gw  = (j >> 1) & 3;

  bf16x8 qf[4];
  {
    const float* qr = Qb + (size_t)(wave * 16 + lr) * DHEAD;
    #pragma unroll
    for (int c = 0; c < 4; ++c) {
      const float4 u0 = *reinterpret_cast<const float4*>(qr + c * 32 + lg * 8);
      const float4 u1 = *reinterpret_cast<const float4*>(qr + c * 32 + lg * 8 + 4);
      bf16x8 f;
      f[0] = (bf16)u0.x; f[1] = (bf16)u0.y; f[2] = (bf16)u0.z; f[3] = (bf16)u0.w;
      f[4] = (bf16)u1.x; f[5] = (bf16)u1.y; f[6] = (bf16)u1.z; f[7] = (bf16)u1.w;
      qf[c] = f;
    }
  }

  f32x4 oacc[8];
  #pragma unroll
  for (int ii = 0; ii < 8; ++ii) oacc[ii] = (f32x4){0.f, 0.f, 0.f, 0.f};
  float m = NINF, l = 0.f;

  const int nt = 2 * (qt + 1);
  float4 kA[2], kB[2], vA[2], vB[2];

  auto load_tile = [&](int kc) {
    #pragma unroll
    for (int ps = 0; ps < 2; ++ps) {
      const int kv = kc + 2 * (prw + 8 * ps);
      const float* kp = Kb + (size_t)kv * DHEAD + d4;
      const float* vp = Vb + (size_t)kv * DHEAD + d4;
      kA[ps] = *reinterpret_cast<const float4*>(kp);
      kB[ps] = *reinterpret_cast<const float4*>(kp + DHEAD);
      vA[ps] = *reinterpret_cast<const float4*>(vp);
      vB[ps] = *reinterpret_cast<const float4*>(vp + DHEAD);
    }
  };
  auto write_tile = [&](int buf) {
    #pragma unroll
    for (int ps = 0; ps < 2; ++ps) {
      const int kvp = prw + 8 * ps;
      bf16x4 ka, kb;
      ka[0] = (bf16)kA[ps].x; ka[1] = (bf16)kA[ps].y;
      ka[2] = (bf16)kA[ps].z; ka[3] = (bf16)kA[ps].w;
      kb[0] = (bf16)kB[ps].x; kb[1] = (bf16)kB[ps].y;
      kb[2] = (bf16)kB[ps].z; kb[3] = (bf16)kB[ps].w;
      *reinterpret_cast<bf16x4*>(&Ks[buf][2 * kvp][d4])     = ka;
      *reinterpret_cast<bf16x4*>(&Ks[buf][2 * kvp + 1][d4]) = kb;
      const int pS = kvp ^ (Gw << 2);
      const float* fa = &vA[ps].x;
      const float* fb = &vB[ps].x;
      #pragma unroll
      for (int c = 0; c < 4; ++c) {
        *reinterpret_cast<unsigned*>(&Vt[buf][d4 + c][2 * pS]) = pk2(fa[c], fb[c]);
      }
    }
  };

  load_tile(0);
  write_tile(0);
  if (nt > 1) load_tile(32);

  int cur = 0;
  for (int t = 0; t < nt; ++t) {
    __syncthreads();
    if (t + 1 < nt) write_tile(cur ^ 1);
    if (t + 2 < nt) load_tile((t + 2) * 32);

    const int kc = t * 32;
    if (kc <= wrow0 + 15) {
      f32x4 s0 = {0.f, 0.f, 0.f, 0.f}, s1 = {0.f, 0.f, 0.f, 0.f};
      __builtin_amdgcn_s_setprio(1);
      #pragma unroll
      for (int c = 0; c < 4; ++c) {
        const bf16x8 kf0 = *reinterpret_cast<const bf16x8*>(&Ks[cur][lr][c * 32 + lg * 8]);
        const bf16x8 kf1 = *reinterpret_cast<const bf16x8*>(&Ks[cur][16 + lr][c * 32 + lg * 8]);
        s0 = __builtin_amdgcn_mfma_f32_16x16x32_bf16(kf0, qf[c], s0, 0, 0, 0);
        s1 = __builtin_amdgcn_mfma_f32_16x16x32_bf16(kf1, qf[c], s1, 0, 0, 0);
      }
      __builtin_amdgcn_s_setprio(0);

      const int qg = wrow0 + lr;
      float x0[4], x1[4];
      if (kc + 31 > wrow0) {
        #pragma unroll
        for (int rr = 0; rr < 4; ++rr) {
          x0[rr] = (kc + 4 * lg + rr      > qg) ? NINF : s0[rr] * SCL2;
          x1[rr] = (kc + 16 + 4 * lg + rr > qg) ? NINF : s1[rr] * SCL2;
        }
      } else {
        #pragma unroll
        for (int rr = 0; rr < 4; ++rr) { x0[rr] = s0[rr] * SCL2; x1[rr] = s1[rr] * SCL2; }
      }
      float tm = NINF;
      #pragma unroll
      for (int rr = 0; rr < 4; ++rr) tm = fmaxf(tm, fmaxf(x0[rr], x1[rr]));
      tm = fmaxf(tm, __shfl_xor(tm, 16));
      tm = fmaxf(tm, __shfl_xor(tm, 32));

      if (!__all(tm <= m + 8.0f)) {
        const float mn = fmaxf(m, tm);
        const float al = __builtin_exp2f(m - mn);
        m = mn; l *= al;
        #pragma unroll
        for (int rr = 0; rr < 4; ++rr) {
          const float ar = __shfl(al, 4 * lg + rr);
          #pragma unroll
          for (int ds = 0; ds < 8; ++ds) oacc[ds][rr] *= ar;
        }
      }

      float p0[4], p1[4];
      float ts = 0.f;
      #pragma unroll
      for (int rr = 0; rr < 4; ++rr) {
        p0[rr] = __builtin_exp2f(x0[rr] - m);
        p1[rr] = __builtin_exp2f(x1[rr] - m);
        ts += p0[rr] + p1[rr];
      }
      ts += __shfl_xor(ts, 16);
      ts += __shfl_xor(ts, 32);
      l += ts;

      *reinterpret_cast<unsigned*>(&Ps[wave][lr][4 * lg])          = pk2(p0[0], p0[1]);
      *reinterpret_cast<unsigned*>(&Ps[wave][lr][4 * lg + 2])      = pk2(p0[2], p0[3]);
      *reinterpret_cast<unsigned*>(&Ps[wave][lr][16 + 4 * lg])     = pk2(p1[0], p1[1]);
      *reinterpret_cast<unsigned*>(&Ps[wave][lr][16 + 4 * lg + 2]) = pk2(p1[2], p1[3]);

      const bf16x8 pf = *reinterpret_cast<const bf16x8*>(&Ps[wave][lr][lg * 8]);
      __builtin_amdgcn_s_setprio(1);
      #pragma unroll
      for (int ds = 0; ds < 8; ++ds) {
        const int G = (2 * ds + (lr >> 3)) & 3;
        const bf16x8 vf = *reinterpret_cast<const bf16x8*>(&Vt[cur][ds * 16 + lr][8 * (lg ^ G)]);
        oacc[ds] = __builtin_amdgcn_mfma_f32_16x16x32_bf16(pf, vf, oacc[ds], 0, 0, 0);
      }
      __builtin_amdgcn_s_setprio(0);
    }
    cur ^= 1;
  }

  const float linv = 1.0f / l;
  float* Ob = O + bo + (size_t)(qt * 64 + wave * 16) * DHEAD;
  #pragma unroll
  for (int rr = 0; rr < 4; ++rr) {
    const float ir = __shfl(linv, 4 * lg + rr);
    #pragma unroll
    for (int ds = 0; ds < 8; ++ds) {
      Ob[(size_t)(4 * lg + rr) * DHEAD + ds * 16 + lr] = oacc[ds][rr] * ir;
    }
  }
}

extern "C" void kernel_launch(void* const* d_in, const int* in_sizes, int n_in,
                              void* d_out, int out_size, void* d_ws, size_t ws_size,
                              hipStream_t stream) {
  const float* q = (const float*)d_in[0];
  const float* k = (const float*)d_in[1];
  const float* v = (const float*)d_in[2];
  float* o = (float*)d_out;

  const int B = 16;
  const int S = in_sizes[0] / (B * DHEAD);   // 2048

  if (ws_size >= WS_NEED && S == 2048) {
    float* ws = (float*)d_ws;
    fa_split<<<dim3(1024), dim3(256), 0, stream>>>(q, k, v, ws, S);
    fa_merge<<<dim3(512), dim3(256), 0, stream>>>(ws, o, S);
  } else {
    fa_fwd<<<dim3(512), dim3(256), 0, stream>>>(q, k, v, o, S);
  }
}